// Round 1
// baseline (2574.442 us; speedup 1.0000x reference)
//
#include <hip/hip_runtime.h>
#include <math.h>

#define NSEG 533
#define CFEAT 2112
#define PIX 160000
#define SIM_THRESH 0.97f

// ---- K3 config: segment feature sums ----
#define CH 24           // channels per block
#define CGRP 88         // 88*24 = 2112
#define PCH 8           // pixel chunks
#define CHUNKQ 5000     // (160000/8)/4 float4-quads per chunk
#define THR3 512

__device__ inline void gAtomAddF(float* p, float v) {
    unsafeAtomicAdd(p, v);   // hardware global_atomic_add_f32
}

// K1: per-segment label histogram (y in {0,1,2})
__global__ __launch_bounds__(256) void k_counts(const int* __restrict__ sp,
                                                const int* __restrict__ y,
                                                int* __restrict__ c3) {
    int p = blockIdx.x * 256 + threadIdx.x;
    if (p < PIX) {
        atomicAdd(&c3[sp[p] * 3 + y[p]], 1);
    }
}

// K2: majority label + tie-break, counts, writes lab/labeled outputs
__global__ __launch_bounds__(256) void k_labels(const int* __restrict__ c3,
                                                int* __restrict__ lab,
                                                float* __restrict__ invc,
                                                float* __restrict__ out) {
    int s = blockIdx.x * 256 + threadIdx.x;
    if (s >= NSEG) return;
    int c0 = c3[s * 3 + 0], c1 = c3[s * 3 + 1], c2 = c3[s * 3 + 2];
    int cnt = c0 + c1 + c2;
    int idx = 0, best = c0;
    if (c1 > best) { best = c1; idx = 1; }
    if (c2 > best) { best = c2; idx = 2; }
    if (idx == 0) idx = (c2 > c1) ? 2 : ((c1 > c2) ? 1 : 0);
    lab[s] = idx;
    invc[s] = 1.0f / (float)(cnt > 0 ? cnt : 1);
    out[1066 + s] = (float)idx;           // lab
    out[1599 + s] = (idx != 0) ? 1.0f : 0.0f; // labeled
}

// K3: segment sums, LDS-privatized per (channel-group, pixel-chunk) block
__global__ __launch_bounds__(THR3) void k_segsum(const float* __restrict__ fm,
                                                 const int* __restrict__ sp,
                                                 float* __restrict__ sums) {
    __shared__ float acc[CH * NSEG];   // [c][s], 51168 B
    int tid = threadIdx.x;
    int cg = blockIdx.x;   // channel group
    int pc = blockIdx.y;   // pixel chunk
    for (int e = tid; e < CH * NSEG; e += THR3) acc[e] = 0.0f;
    __syncthreads();

    int c0 = cg * CH;
    int q0 = pc * CHUNKQ;
    const int4* sp4 = (const int4*)sp;
    const float4* fm4 = (const float4*)fm;
    for (int q = tid; q < CHUNKQ; q += THR3) {
        int4 s4 = sp4[q0 + q];
        size_t base = (size_t)c0 * (PIX / 4) + q0 + q;
        #pragma unroll
        for (int c = 0; c < CH; c++) {
            float4 v = fm4[base + (size_t)c * (PIX / 4)];
            atomicAdd(&acc[c * NSEG + s4.x], v.x);
            atomicAdd(&acc[c * NSEG + s4.y], v.y);
            atomicAdd(&acc[c * NSEG + s4.z], v.z);
            atomicAdd(&acc[c * NSEG + s4.w], v.w);
        }
    }
    __syncthreads();
    // flush: s-major for semi-coalesced global atomics
    for (int e = tid; e < CH * NSEG; e += THR3) {
        int s = e / CH, c = e % CH;
        gAtomAddF(&sums[(size_t)s * CFEAT + c0 + c], acc[c * NSEG + s]);
    }
}

// K4: mean (in place over sums) + inverse row norm
__global__ __launch_bounds__(256) void k_mean(float* __restrict__ feat,
                                              const float* __restrict__ invc,
                                              float* __restrict__ invn) {
    int s = blockIdx.x;
    float ic = invc[s];
    float ss = 0.0f;
    for (int c = threadIdx.x; c < CFEAT; c += 256) {
        float v = feat[(size_t)s * CFEAT + c] * ic;
        feat[(size_t)s * CFEAT + c] = v;
        ss += v * v;
    }
    __shared__ float red[256];
    red[threadIdx.x] = ss;
    __syncthreads();
    for (int st = 128; st > 0; st >>= 1) {
        if (threadIdx.x < st) red[threadIdx.x] += red[threadIdx.x + st];
        __syncthreads();
    }
    if (threadIdx.x == 0) invn[s] = 1.0f / fmaxf(sqrtf(red[0]), 1e-12f);
}

// Generic f32 GEMM: C = [relu](A @ B + bias). A: MxK row-major.
// TRANSB=0: B is KxN row-major. TRANSB=1: B is NxK row-major (C=A@B^T).
template <int TRANSB, int RELU>
__global__ __launch_bounds__(256) void gemm_f32(const float* __restrict__ A,
                                                const float* __restrict__ B,
                                                const float* __restrict__ bias,
                                                float* __restrict__ C,
                                                int M, int N, int K) {
    __shared__ float As[16][68];
    __shared__ float Bs[16][68];
    int tid = threadIdx.x;
    int col0 = blockIdx.x * 64;
    int row0 = blockIdx.y * 64;
    int tx = tid & 15, ty = tid >> 4;
    float acc[4][4] = {};
    for (int k0 = 0; k0 < K; k0 += 16) {
        #pragma unroll
        for (int l = 0; l < 4; l++) {
            int e = tid + l * 256;
            int r = e >> 4, kk = e & 15;
            int gr = row0 + r;
            float v = 0.0f;
            if (gr < M) v = A[(size_t)gr * K + k0 + kk];
            As[kk][r] = v;
        }
        #pragma unroll
        for (int l = 0; l < 4; l++) {
            int e = tid + l * 256;
            if (TRANSB) {
                int r = e >> 4, kk = e & 15;
                int gn = col0 + r;
                float v = 0.0f;
                if (gn < N) v = B[(size_t)gn * K + k0 + kk];
                Bs[kk][r] = v;
            } else {
                int kk = e >> 6, n = e & 63;
                int gn = col0 + n;
                float v = 0.0f;
                if (gn < N) v = B[(size_t)(k0 + kk) * N + gn];
                Bs[kk][n] = v;
            }
        }
        __syncthreads();
        #pragma unroll
        for (int kk = 0; kk < 16; kk++) {
            float a[4], b[4];
            #pragma unroll
            for (int i = 0; i < 4; i++) a[i] = As[kk][ty * 4 + i];
            #pragma unroll
            for (int j = 0; j < 4; j++) b[j] = Bs[kk][tx * 4 + j];
            #pragma unroll
            for (int i = 0; i < 4; i++)
                #pragma unroll
                for (int j = 0; j < 4; j++) acc[i][j] += a[i] * b[j];
        }
        __syncthreads();
    }
    #pragma unroll
    for (int i = 0; i < 4; i++) {
        int gr = row0 + ty * 4 + i;
        if (gr >= M) continue;
        #pragma unroll
        for (int j = 0; j < 4; j++) {
            int gc = col0 + tx * 4 + j;
            if (gc >= N) continue;
            float v = acc[i][j];
            if (bias) v += bias[gc];
            if (RELU) v = fmaxf(v, 0.0f);
            C[(size_t)gr * N + gc] = v;
        }
    }
}

// K6: masked row-max/argmax over affinity + label propagation
__global__ __launch_bounds__(256) void k_prop(const float* __restrict__ aff,
                                              const int* __restrict__ lab,
                                              const float* __restrict__ invn,
                                              float* __restrict__ out) {
    int i = blockIdx.x;
    float invi = invn[i];
    float best = -INFINITY;
    int bidx = 0;
    for (int j = threadIdx.x; j < NSEG; j += 256) {
        if (lab[j] != 0) {
            float v = aff[(size_t)i * NSEG + j] * invi * invn[j];
            if (v > best) { best = v; bidx = j; }  // ascending j keeps first-max
        }
    }
    __shared__ float bv[256];
    __shared__ int bi[256];
    bv[threadIdx.x] = best;
    bi[threadIdx.x] = bidx;
    __syncthreads();
    for (int st = 128; st > 0; st >>= 1) {
        if (threadIdx.x < st) {
            float v2 = bv[threadIdx.x + st];
            int i2 = bi[threadIdx.x + st];
            if (v2 > bv[threadIdx.x] ||
                (v2 == bv[threadIdx.x] && i2 < bi[threadIdx.x])) {
                bv[threadIdx.x] = v2;
                bi[threadIdx.x] = i2;
            }
        }
        __syncthreads();
    }
    if (threadIdx.x == 0) {
        int li = lab[i];
        int nl = li;
        if (li == 0 && bv[0] >= SIM_THRESH) nl = lab[bi[0]];
        out[2132 + i] = (float)nl;
    }
}

// K7: final 32->2 head + softmax -> preds
__global__ __launch_bounds__(256) void k_head(const float* __restrict__ h3,
                                              const float* __restrict__ wc,
                                              const float* __restrict__ bc,
                                              float* __restrict__ out) {
    int s = blockIdx.x * 256 + threadIdx.x;
    if (s >= NSEG) return;
    float z0 = bc[0], z1 = bc[1];
    #pragma unroll
    for (int k = 0; k < 32; k++) {
        float h = h3[s * 32 + k];
        z0 += h * wc[k * 2 + 0];
        z1 += h * wc[k * 2 + 1];
    }
    float m = fmaxf(z0, z1);
    float e0 = expf(z0 - m), e1 = expf(z1 - m);
    float inv = 1.0f / (e0 + e1);
    out[s * 2 + 0] = e0 * inv;
    out[s * 2 + 1] = e1 * inv;
}

extern "C" void kernel_launch(void* const* d_in, const int* in_sizes, int n_in,
                              void* d_out, int out_size, void* d_ws, size_t ws_size,
                              hipStream_t stream) {
    const float* fm = (const float*)d_in[0];
    const int* sp   = (const int*)d_in[1];
    const int* y    = (const int*)d_in[2];
    const float* w1 = (const float*)d_in[3];
    const float* b1 = (const float*)d_in[4];
    const float* w2 = (const float*)d_in[5];
    const float* b2 = (const float*)d_in[6];
    const float* w3 = (const float*)d_in[7];
    const float* b3 = (const float*)d_in[8];
    const float* wc = (const float*)d_in[9];
    const float* bc = (const float*)d_in[10];
    float* out = (float*)d_out;
    char* ws = (char*)d_ws;

    size_t off = 0;
    auto alloc = [&](size_t bytes) {
        size_t o = off;
        off += (bytes + 255) & ~(size_t)255;
        return o;
    };
    float* feat = (float*)(ws + alloc((size_t)NSEG * CFEAT * 4)); // sums -> mean
    int*   c3   = (int*)(ws + alloc((size_t)NSEG * 3 * 4));
    int*   lab  = (int*)(ws + alloc((size_t)NSEG * 4));
    float* invc = (float*)(ws + alloc((size_t)NSEG * 4));
    float* invn = (float*)(ws + alloc((size_t)NSEG * 4));
    float* h1   = (float*)(ws + alloc((size_t)NSEG * 1024 * 4));
    float* h2   = (float*)(ws + alloc((size_t)NSEG * 1024 * 4));
    float* h3   = (float*)(ws + alloc((size_t)NSEG * 32 * 4));
    float* aff  = (float*)(ws + alloc((size_t)NSEG * NSEG * 4));

    // zero the accumulators (ws is NOT re-poisoned between replays)
    hipMemsetAsync(feat, 0, (size_t)NSEG * CFEAT * 4, stream);
    hipMemsetAsync(c3, 0, (size_t)NSEG * 3 * 4, stream);

    k_counts<<<(PIX + 255) / 256, 256, 0, stream>>>(sp, y, c3);
    k_labels<<<3, 256, 0, stream>>>(c3, lab, invc, out);
    k_segsum<<<dim3(CGRP, PCH), THR3, 0, stream>>>(fm, sp, feat);
    k_mean<<<NSEG, 256, 0, stream>>>(feat, invc, invn);

    // MLP: 533x2112 @ 2112x1024 -> @1024x1024 -> @1024x32 (all +bias, relu)
    gemm_f32<0, 1><<<dim3(16, 9), 256, 0, stream>>>(feat, w1, b1, h1, NSEG, 1024, CFEAT);
    gemm_f32<0, 1><<<dim3(16, 9), 256, 0, stream>>>(h1, w2, b2, h2, NSEG, 1024, 1024);
    gemm_f32<0, 1><<<dim3(1, 9), 256, 0, stream>>>(h2, w3, b3, h3, NSEG, 32, 1024);

    // affinity (un-normalized dot products; norms applied in k_prop)
    gemm_f32<1, 0><<<dim3(9, 9), 256, 0, stream>>>(feat, feat, nullptr, aff, NSEG, NSEG, CFEAT);

    k_head<<<3, 256, 0, stream>>>(h3, wc, bc, out);
    k_prop<<<NSEG, 256, 0, stream>>>(aff, lab, invn, out);
}

// Round 2
// 1594.562 us; speedup vs baseline: 1.6145x; 1.6145x over previous
//
#include <hip/hip_runtime.h>
#include <math.h>

#define NSEG 533
#define CFEAT 2112
#define PIX 160000
#define SIM_THRESH 0.97f

typedef __attribute__((ext_vector_type(4))) float f32x4;
typedef __attribute__((ext_vector_type(4))) int   i32x4;
typedef __attribute__((ext_vector_type(8))) short bf16x8;

__device__ inline unsigned int f2bf_rne(float f) {
    unsigned int u = __builtin_bit_cast(unsigned int, f);
    return (u + 0x7FFFu + ((u >> 16) & 1u)) >> 16;   // round-nearest-even bf16
}

// K1: per-segment label histogram (y in {0,1,2})
__global__ __launch_bounds__(256) void k_counts(const int* __restrict__ sp,
                                                const int* __restrict__ y,
                                                int* __restrict__ c3) {
    int p = blockIdx.x * 256 + threadIdx.x;
    if (p < PIX) {
        atomicAdd(&c3[sp[p] * 3 + y[p]], 1);
    }
}

// K2: majority label + tie-break, counts, writes lab/labeled outputs
__global__ __launch_bounds__(256) void k_labels(const int* __restrict__ c3,
                                                int* __restrict__ lab,
                                                float* __restrict__ invc,
                                                float* __restrict__ out) {
    int s = blockIdx.x * 256 + threadIdx.x;
    if (s >= NSEG) return;
    int c0 = c3[s * 3 + 0], c1 = c3[s * 3 + 1], c2 = c3[s * 3 + 2];
    int cnt = c0 + c1 + c2;
    int idx = 0, best = c0;
    if (c1 > best) { best = c1; idx = 1; }
    if (c2 > best) { best = c2; idx = 2; }
    if (idx == 0) idx = (c2 > c1) ? 2 : ((c1 > c2) ? 1 : 0);
    lab[s] = idx;
    invc[s] = 1.0f / (float)(cnt > 0 ? cnt : 1);
    out[1066 + s] = (float)idx;               // lab
    out[1599 + s] = (idx != 0) ? 1.0f : 0.0f; // labeled
}

// K3: segment sums as dense onehot-MFMA GEMM.
// sums[544][2112] += onehot(seg)[544 x 32pix] @ feats[32pix x ch] per K-step.
// Block = 128 thr (2 waves). Wave covers 32 channels (2 N-tiles of 16).
// grid.x = 33 (64-ch groups), grid.y = 31 (pixel ranges).
// A-frag (onehot) built in regs from sp; B-frag from fm with f32->bf16 cvt.
// Any lane->k permutation mismatch cancels (same map used for A and B).
__global__ __launch_bounds__(128, 1) void k_segsum_mfma(const float* __restrict__ fm,
                                                        const int* __restrict__ sp,
                                                        float* __restrict__ sums) {
    const int lane = threadIdx.x & 63;
    const int wave = threadIdx.x >> 6;     // 0..1
    const int r  = lane & 15;              // A row / B col / C col
    const int kg = lane >> 4;              // k-group (8 pixels each)
    const int c0 = blockIdx.x * 64 + wave * 32;

    // pixel-step range for this block (5000 global steps of 32 pixels)
    const int bstep = (int)(((long long)blockIdx.y * 5000) / 31);
    const int estep = (int)(((long long)(blockIdx.y + 1) * 5000) / 31);
    const int nst = estep - bstep;

    const float* b0p = fm + (size_t)(c0 + r) * PIX + (size_t)bstep * 32 + kg * 8;
    const float* b1p = b0p + (size_t)16 * PIX;
    const int*   spp = sp + (size_t)bstep * 32 + kg * 8;

    f32x4 acc[34][2] = {};

    // prefetch step 0
    f32x4 a0n = *(const f32x4*)(b0p);
    f32x4 a1n = *(const f32x4*)(b0p + 4);
    f32x4 b0n = *(const f32x4*)(b1p);
    f32x4 b1n = *(const f32x4*)(b1p + 4);
    i32x4 s0n = *(const i32x4*)(spp);
    i32x4 s1n = *(const i32x4*)(spp + 4);

    for (int st = 0; st < nst; ++st) {
        f32x4 a0 = a0n, a1 = a1n, b0 = b0n, b1 = b1n;
        i32x4 s0 = s0n, s1 = s1n;
        if (st + 1 < nst) {   // prefetch next step (wave-uniform branch)
            size_t off = (size_t)(st + 1) * 32;
            a0n = *(const f32x4*)(b0p + off);
            a1n = *(const f32x4*)(b0p + off + 4);
            b0n = *(const f32x4*)(b1p + off);
            b1n = *(const f32x4*)(b1p + off + 4);
            s0n = *(const i32x4*)(spp + off);
            s1n = *(const i32x4*)(spp + off + 4);
        }

        // pack B fragments: 8 f32 -> 8 bf16 (4 u32)
        unsigned int fb0[4], fb1[4];
        #pragma unroll
        for (int t = 0; t < 2; ++t) {
            fb0[t]     = f2bf_rne(a0[2 * t]) | (f2bf_rne(a0[2 * t + 1]) << 16);
            fb0[t + 2] = f2bf_rne(a1[2 * t]) | (f2bf_rne(a1[2 * t + 1]) << 16);
            fb1[t]     = f2bf_rne(b0[2 * t]) | (f2bf_rne(b0[2 * t + 1]) << 16);
            fb1[t + 2] = f2bf_rne(b1[2 * t]) | (f2bf_rne(b1[2 * t + 1]) << 16);
        }
        bf16x8 vb0 = __builtin_bit_cast(bf16x8, fb0);
        bf16x8 vb1 = __builtin_bit_cast(bf16x8, fb1);

        int seg[8] = { s0[0], s0[1], s0[2], s0[3], s1[0], s1[1], s1[2], s1[3] };

        #pragma unroll
        for (int m = 0; m < 34; ++m) {
            int tgt = m * 16 + r;
            unsigned int w[4];
            #pragma unroll
            for (int t = 0; t < 4; ++t) {
                w[t] = ((seg[2 * t]     == tgt) ? 0x00003F80u : 0u) |
                       ((seg[2 * t + 1] == tgt) ? 0x3F800000u : 0u);
            }
            bf16x8 va = __builtin_bit_cast(bf16x8, w);
            acc[m][0] = __builtin_amdgcn_mfma_f32_16x16x32_bf16(va, vb0, acc[m][0], 0, 0, 0);
            acc[m][1] = __builtin_amdgcn_mfma_f32_16x16x32_bf16(va, vb1, acc[m][1], 0, 0, 0);
        }
    }

    // flush: C/D layout col=lane&15 (channel), row=(lane>>4)*4+q (segment)
    #pragma unroll
    for (int m = 0; m < 34; ++m) {
        #pragma unroll
        for (int t = 0; t < 2; ++t) {
            #pragma unroll
            for (int q = 0; q < 4; ++q) {
                int s = m * 16 + kg * 4 + q;
                if (s < NSEG) {
                    unsafeAtomicAdd(&sums[(size_t)s * CFEAT + c0 + t * 16 + r],
                                    acc[m][t][q]);
                }
            }
        }
    }
}

// K4: mean (in place over sums) + inverse row norm
__global__ __launch_bounds__(256) void k_mean(float* __restrict__ feat,
                                              const float* __restrict__ invc,
                                              float* __restrict__ invn) {
    int s = blockIdx.x;
    float ic = invc[s];
    float ss = 0.0f;
    for (int c = threadIdx.x; c < CFEAT; c += 256) {
        float v = feat[(size_t)s * CFEAT + c] * ic;
        feat[(size_t)s * CFEAT + c] = v;
        ss += v * v;
    }
    __shared__ float red[256];
    red[threadIdx.x] = ss;
    __syncthreads();
    for (int st = 128; st > 0; st >>= 1) {
        if (threadIdx.x < st) red[threadIdx.x] += red[threadIdx.x + st];
        __syncthreads();
    }
    if (threadIdx.x == 0) invn[s] = 1.0f / fmaxf(sqrtf(red[0]), 1e-12f);
}

// Generic f32 GEMM: C = [relu](A @ B + bias). A: MxK row-major.
// TRANSB=0: B is KxN row-major. TRANSB=1: B is NxK row-major (C=A@B^T).
template <int TRANSB, int RELU>
__global__ __launch_bounds__(256) void gemm_f32(const float* __restrict__ A,
                                                const float* __restrict__ B,
                                                const float* __restrict__ bias,
                                                float* __restrict__ C,
                                                int M, int N, int K) {
    __shared__ float As[16][68];
    __shared__ float Bs[16][68];
    int tid = threadIdx.x;
    int col0 = blockIdx.x * 64;
    int row0 = blockIdx.y * 64;
    int tx = tid & 15, ty = tid >> 4;
    float acc[4][4] = {};
    for (int k0 = 0; k0 < K; k0 += 16) {
        #pragma unroll
        for (int l = 0; l < 4; l++) {
            int e = tid + l * 256;
            int r = e >> 4, kk = e & 15;
            int gr = row0 + r;
            float v = 0.0f;
            if (gr < M) v = A[(size_t)gr * K + k0 + kk];
            As[kk][r] = v;
        }
        #pragma unroll
        for (int l = 0; l < 4; l++) {
            int e = tid + l * 256;
            if (TRANSB) {
                int r = e >> 4, kk = e & 15;
                int gn = col0 + r;
                float v = 0.0f;
                if (gn < N) v = B[(size_t)gn * K + k0 + kk];
                Bs[kk][r] = v;
            } else {
                int kk = e >> 6, n = e & 63;
                int gn = col0 + n;
                float v = 0.0f;
                if (gn < N) v = B[(size_t)(k0 + kk) * N + gn];
                Bs[kk][n] = v;
            }
        }
        __syncthreads();
        #pragma unroll
        for (int kk = 0; kk < 16; kk++) {
            float a[4], b[4];
            #pragma unroll
            for (int i = 0; i < 4; i++) a[i] = As[kk][ty * 4 + i];
            #pragma unroll
            for (int j = 0; j < 4; j++) b[j] = Bs[kk][tx * 4 + j];
            #pragma unroll
            for (int i = 0; i < 4; i++)
                #pragma unroll
                for (int j = 0; j < 4; j++) acc[i][j] += a[i] * b[j];
        }
        __syncthreads();
    }
    #pragma unroll
    for (int i = 0; i < 4; i++) {
        int gr = row0 + ty * 4 + i;
        if (gr >= M) continue;
        #pragma unroll
        for (int j = 0; j < 4; j++) {
            int gc = col0 + tx * 4 + j;
            if (gc >= N) continue;
            float v = acc[i][j];
            if (bias) v += bias[gc];
            if (RELU) v = fmaxf(v, 0.0f);
            C[(size_t)gr * N + gc] = v;
        }
    }
}

// K6: masked row-max/argmax over affinity + label propagation
__global__ __launch_bounds__(256) void k_prop(const float* __restrict__ aff,
                                              const int* __restrict__ lab,
                                              const float* __restrict__ invn,
                                              float* __restrict__ out) {
    int i = blockIdx.x;
    float invi = invn[i];
    float best = -INFINITY;
    int bidx = 0;
    for (int j = threadIdx.x; j < NSEG; j += 256) {
        if (lab[j] != 0) {
            float v = aff[(size_t)i * NSEG + j] * invi * invn[j];
            if (v > best) { best = v; bidx = j; }
        }
    }
    __shared__ float bv[256];
    __shared__ int bi[256];
    bv[threadIdx.x] = best;
    bi[threadIdx.x] = bidx;
    __syncthreads();
    for (int st = 128; st > 0; st >>= 1) {
        if (threadIdx.x < st) {
            float v2 = bv[threadIdx.x + st];
            int i2 = bi[threadIdx.x + st];
            if (v2 > bv[threadIdx.x] ||
                (v2 == bv[threadIdx.x] && i2 < bi[threadIdx.x])) {
                bv[threadIdx.x] = v2;
                bi[threadIdx.x] = i2;
            }
        }
        __syncthreads();
    }
    if (threadIdx.x == 0) {
        int li = lab[i];
        int nl = li;
        if (li == 0 && bv[0] >= SIM_THRESH) nl = lab[bi[0]];
        out[2132 + i] = (float)nl;
    }
}

// K7: final 32->2 head + softmax -> preds
__global__ __launch_bounds__(256) void k_head(const float* __restrict__ h3,
                                              const float* __restrict__ wc,
                                              const float* __restrict__ bc,
                                              float* __restrict__ out) {
    int s = blockIdx.x * 256 + threadIdx.x;
    if (s >= NSEG) return;
    float z0 = bc[0], z1 = bc[1];
    #pragma unroll
    for (int k = 0; k < 32; k++) {
        float h = h3[s * 32 + k];
        z0 += h * wc[k * 2 + 0];
        z1 += h * wc[k * 2 + 1];
    }
    float m = fmaxf(z0, z1);
    float e0 = expf(z0 - m), e1 = expf(z1 - m);
    float inv = 1.0f / (e0 + e1);
    out[s * 2 + 0] = e0 * inv;
    out[s * 2 + 1] = e1 * inv;
}

extern "C" void kernel_launch(void* const* d_in, const int* in_sizes, int n_in,
                              void* d_out, int out_size, void* d_ws, size_t ws_size,
                              hipStream_t stream) {
    const float* fm = (const float*)d_in[0];
    const int* sp   = (const int*)d_in[1];
    const int* y    = (const int*)d_in[2];
    const float* w1 = (const float*)d_in[3];
    const float* b1 = (const float*)d_in[4];
    const float* w2 = (const float*)d_in[5];
    const float* b2 = (const float*)d_in[6];
    const float* w3 = (const float*)d_in[7];
    const float* b3 = (const float*)d_in[8];
    const float* wc = (const float*)d_in[9];
    const float* bc = (const float*)d_in[10];
    float* out = (float*)d_out;
    char* ws = (char*)d_ws;

    size_t off = 0;
    auto alloc = [&](size_t bytes) {
        size_t o = off;
        off += (bytes + 255) & ~(size_t)255;
        return o;
    };
    float* feat = (float*)(ws + alloc((size_t)NSEG * CFEAT * 4)); // sums -> mean
    int*   c3   = (int*)(ws + alloc((size_t)NSEG * 3 * 4));
    int*   lab  = (int*)(ws + alloc((size_t)NSEG * 4));
    float* invc = (float*)(ws + alloc((size_t)NSEG * 4));
    float* invn = (float*)(ws + alloc((size_t)NSEG * 4));
    float* h1   = (float*)(ws + alloc((size_t)NSEG * 1024 * 4));
    float* h2   = (float*)(ws + alloc((size_t)NSEG * 1024 * 4));
    float* h3   = (float*)(ws + alloc((size_t)NSEG * 32 * 4));
    float* aff  = (float*)(ws + alloc((size_t)NSEG * NSEG * 4));

    // zero the accumulators (ws is NOT re-poisoned between replays)
    hipMemsetAsync(feat, 0, (size_t)NSEG * CFEAT * 4, stream);
    hipMemsetAsync(c3, 0, (size_t)NSEG * 3 * 4, stream);

    k_counts<<<(PIX + 255) / 256, 256, 0, stream>>>(sp, y, c3);
    k_labels<<<3, 256, 0, stream>>>(c3, lab, invc, out);
    k_segsum_mfma<<<dim3(33, 31), 128, 0, stream>>>(fm, sp, feat);
    k_mean<<<NSEG, 256, 0, stream>>>(feat, invc, invn);

    // MLP: 533x2112 @ 2112x1024 -> @1024x1024 -> @1024x32 (all +bias, relu)
    gemm_f32<0, 1><<<dim3(16, 9), 256, 0, stream>>>(feat, w1, b1, h1, NSEG, 1024, CFEAT);
    gemm_f32<0, 1><<<dim3(16, 9), 256, 0, stream>>>(h1, w2, b2, h2, NSEG, 1024, 1024);
    gemm_f32<0, 1><<<dim3(1, 9), 256, 0, stream>>>(h2, w3, b3, h3, NSEG, 32, 1024);

    // affinity (un-normalized dot products; norms applied in k_prop)
    gemm_f32<1, 0><<<dim3(9, 9), 256, 0, stream>>>(feat, feat, nullptr, aff, NSEG, NSEG, CFEAT);

    k_head<<<3, 256, 0, stream>>>(h3, wc, bc, out);
    k_prop<<<NSEG, 256, 0, stream>>>(aff, lab, invn, out);
}

// Round 3
// 1216.366 us; speedup vs baseline: 2.1165x; 1.3109x over previous
//
#include <hip/hip_runtime.h>
#include <math.h>

#define NSEG 533
#define CFEAT 2112
#define PIX 160000
#define SIM_THRESH 0.97f
#define KC 16   // segsum K-chunks: 33*16*4 waves = 2112 ~= one full 2/SIMD round

typedef __attribute__((ext_vector_type(4))) float f32x4;
typedef __attribute__((ext_vector_type(4))) int   i32x4;
typedef __attribute__((ext_vector_type(8))) short bf16x8;

__device__ inline unsigned short f2bf_u16(float f) {
    unsigned u = __builtin_bit_cast(unsigned, f);
    return (unsigned short)((u + 0x7FFFu + ((u >> 16) & 1u)) >> 16);
}
__device__ inline unsigned pkbf(float a, float b) {   // low=bf16(a), high=bf16(b)
    unsigned r;
    asm("v_cvt_pk_bf16_f32 %0, %1, %2" : "=v"(r) : "v"(a), "v"(b));
    return r;
}

// K1: per-segment label histogram (y in {0,1,2})
__global__ __launch_bounds__(256) void k_counts(const int* __restrict__ sp,
                                                const int* __restrict__ y,
                                                int* __restrict__ c3) {
    int p = blockIdx.x * 256 + threadIdx.x;
    if (p < PIX) atomicAdd(&c3[sp[p] * 3 + y[p]], 1);
}

// K2: majority label + tie-break, writes lab/labeled outputs
__global__ __launch_bounds__(256) void k_labels(const int* __restrict__ c3,
                                                int* __restrict__ lab,
                                                float* __restrict__ invc,
                                                float* __restrict__ out) {
    int s = blockIdx.x * 256 + threadIdx.x;
    if (s >= NSEG) return;
    int c0 = c3[s * 3 + 0], c1 = c3[s * 3 + 1], c2 = c3[s * 3 + 2];
    int cnt = c0 + c1 + c2;
    int idx = 0, best = c0;
    if (c1 > best) { best = c1; idx = 1; }
    if (c2 > best) { best = c2; idx = 2; }
    if (idx == 0) idx = (c2 > c1) ? 2 : ((c1 > c2) ? 1 : 0);
    lab[s] = idx;
    invc[s] = 1.0f / (float)(cnt > 0 ? cnt : 1);
    out[1066 + s] = (float)idx;
    out[1599 + s] = (idx != 0) ? 1.0f : 0.0f;
}

// K3: segment sums as onehot-MFMA GEMM, v2.
// Block = 256 thr (4 waves). Block covers 64 channels x all 544 segs.
// Waves split the 34 M-tiles {9,9,8,8}; all waves share the same B (L2-hit).
// acc[9][4] f32x4 = 144 VGPR -> 2 waves/SIMD.
__global__ __launch_bounds__(256, 2) void k_segsum_mfma(const float* __restrict__ fm,
                                                        const int* __restrict__ sp,
                                                        float* __restrict__ sums) {
    const int lane = threadIdx.x & 63;
    const int wave = threadIdx.x >> 6;
    const int r = lane & 15, kg = lane >> 4;
    const int c0 = blockIdx.x * 64;
    const int mt0 = (wave < 2) ? wave * 9 : 18 + (wave - 2) * 8;
    const int cnt = (wave < 2) ? 9 : 8;
    const int tbase = mt0 * 16 + r;

    const int bstep = (int)(((long long)blockIdx.y * (PIX / 32)) / KC);
    const int estep = (int)(((long long)(blockIdx.y + 1) * (PIX / 32)) / KC);
    const int nst = estep - bstep;

    const float* bp0 = fm + (size_t)(c0 + r) * PIX + (size_t)bstep * 32 + kg * 8;
    const float* bp1 = bp0 + (size_t)16 * PIX;
    const float* bp2 = bp0 + (size_t)32 * PIX;
    const float* bp3 = bp0 + (size_t)48 * PIX;
    const int* spp = sp + (size_t)bstep * 32 + kg * 8;

    f32x4 acc[9][4] = {};

    i32x4 sA = *(const i32x4*)spp;
    i32x4 sB = *(const i32x4*)(spp + 4);

    for (int st = 0; st < nst; ++st) {
        const size_t o = (size_t)st * 32;
        f32x4 f0 = *(const f32x4*)(bp0 + o);
        f32x4 f1 = *(const f32x4*)(bp0 + o + 4);
        f32x4 f2 = *(const f32x4*)(bp1 + o);
        f32x4 f3 = *(const f32x4*)(bp1 + o + 4);
        f32x4 f4 = *(const f32x4*)(bp2 + o);
        f32x4 f5 = *(const f32x4*)(bp2 + o + 4);
        f32x4 f6 = *(const f32x4*)(bp3 + o);
        f32x4 f7 = *(const f32x4*)(bp3 + o + 4);
        i32x4 s0 = sA, s1 = sB;
        if (st + 1 < nst) {
            sA = *(const i32x4*)(spp + o + 32);
            sB = *(const i32x4*)(spp + o + 36);
        }
        int seg[8] = { s0[0], s0[1], s0[2], s0[3], s1[0], s1[1], s1[2], s1[3] };

        // A-build first: pure VALU on prefetched seg -> hides the B-load latency
        unsigned aw[9][4];
        #pragma unroll
        for (int i = 0; i < 9; ++i) {
            if (i < cnt) {
                const int tgt = tbase + i * 16;
                #pragma unroll
                for (int t = 0; t < 4; ++t) {
                    aw[i][t] = ((seg[2 * t]     == tgt) ? 0x00003F80u : 0u) |
                               ((seg[2 * t + 1] == tgt) ? 0x3F800000u : 0u);
                }
            }
        }
        // pack B: 32 f32 -> 16 packed bf16 words
        uint4 wb0 = { pkbf(f0[0], f0[1]), pkbf(f0[2], f0[3]), pkbf(f1[0], f1[1]), pkbf(f1[2], f1[3]) };
        uint4 wb1 = { pkbf(f2[0], f2[1]), pkbf(f2[2], f2[3]), pkbf(f3[0], f3[1]), pkbf(f3[2], f3[3]) };
        uint4 wb2 = { pkbf(f4[0], f4[1]), pkbf(f4[2], f4[3]), pkbf(f5[0], f5[1]), pkbf(f5[2], f5[3]) };
        uint4 wb3 = { pkbf(f6[0], f6[1]), pkbf(f6[2], f6[3]), pkbf(f7[0], f7[1]), pkbf(f7[2], f7[3]) };
        bf16x8 vb0 = __builtin_bit_cast(bf16x8, wb0);
        bf16x8 vb1 = __builtin_bit_cast(bf16x8, wb1);
        bf16x8 vb2 = __builtin_bit_cast(bf16x8, wb2);
        bf16x8 vb3 = __builtin_bit_cast(bf16x8, wb3);

        #pragma unroll
        for (int i = 0; i < 9; ++i) {
            if (i < cnt) {
                uint4 w4 = { aw[i][0], aw[i][1], aw[i][2], aw[i][3] };
                bf16x8 va = __builtin_bit_cast(bf16x8, w4);
                acc[i][0] = __builtin_amdgcn_mfma_f32_16x16x32_bf16(va, vb0, acc[i][0], 0, 0, 0);
                acc[i][1] = __builtin_amdgcn_mfma_f32_16x16x32_bf16(va, vb1, acc[i][1], 0, 0, 0);
                acc[i][2] = __builtin_amdgcn_mfma_f32_16x16x32_bf16(va, vb2, acc[i][2], 0, 0, 0);
                acc[i][3] = __builtin_amdgcn_mfma_f32_16x16x32_bf16(va, vb3, acc[i][3], 0, 0, 0);
            }
        }
    }

    // flush: C/D col(channel)=lane&15, row(segment)=kg*4+q
    #pragma unroll
    for (int i = 0; i < 9; ++i) {
        if (i < cnt) {
            int tm = mt0 + i;
            #pragma unroll
            for (int nt = 0; nt < 4; ++nt) {
                #pragma unroll
                for (int q = 0; q < 4; ++q) {
                    int s = tm * 16 + kg * 4 + q;
                    if (s < NSEG) {
                        unsafeAtomicAdd(&sums[(size_t)s * CFEAT + c0 + nt * 16 + r],
                                        acc[i][nt][q]);
                    }
                }
            }
        }
    }
}

// K4: mean (in place) + bf16 copy + inverse row norm
__global__ __launch_bounds__(256) void k_mean(float* __restrict__ feat,
                                              unsigned short* __restrict__ featbf,
                                              const float* __restrict__ invc,
                                              float* __restrict__ invn) {
    int s = blockIdx.x;
    float ic = invc[s];
    float ss = 0.0f;
    for (int c = threadIdx.x; c < CFEAT; c += 256) {
        float v = feat[(size_t)s * CFEAT + c] * ic;
        feat[(size_t)s * CFEAT + c] = v;
        featbf[(size_t)s * CFEAT + c] = f2bf_u16(v);
        ss += v * v;
    }
    __shared__ float red[256];
    red[threadIdx.x] = ss;
    __syncthreads();
    for (int st = 128; st > 0; st >>= 1) {
        if (threadIdx.x < st) red[threadIdx.x] += red[threadIdx.x + st];
        __syncthreads();
    }
    if (threadIdx.x == 0) invn[s] = 1.0f / fmaxf(sqrtf(red[0]), 1e-12f);
}

// Transpose + f32->bf16 convert: outT[n][k] = bf16(in[k][n]). Dims mult of 32.
__global__ __launch_bounds__(256) void k_cvtT(const float* __restrict__ in,
                                              unsigned short* __restrict__ outT,
                                              int K, int N) {
    __shared__ float s[32][33];
    int n0 = blockIdx.x * 32, k0 = blockIdx.y * 32;
    int lx = threadIdx.x & 31, ly = threadIdx.x >> 5;   // ly 0..7
    #pragma unroll
    for (int p = 0; p < 4; ++p)
        s[ly + p * 8][lx] = in[(size_t)(k0 + ly + p * 8) * N + n0 + lx];
    __syncthreads();
    #pragma unroll
    for (int p = 0; p < 4; ++p)
        outT[(size_t)(n0 + ly + p * 8) * K + k0 + lx] = f2bf_u16(s[lx][ly + p * 8]);
}

// bf16 MFMA GEMM: C[M][N] = act(A[M][K] @ Bt[N][K]^T + bias).
// 64x64 tile, BK=64, 4 waves (wave = M-quarter). XOR-swizzled LDS (16B-chunk safe).
template <int RELU>
__global__ __launch_bounds__(256) void gemm_bf16(const unsigned short* __restrict__ A,
                                                 const unsigned short* __restrict__ Bt,
                                                 const float* __restrict__ bias,
                                                 float* __restrict__ Cf,
                                                 unsigned short* __restrict__ Cb,
                                                 int M, int N, int K) {
    __shared__ char As[64 * 128];
    __shared__ char Bs[64 * 128];
    const int tid = threadIdx.x;
    const int lane = tid & 63, wave = tid >> 6;
    const int r = lane & 15, kg = lane >> 4;
    const int m0 = blockIdx.y * 64, n0 = blockIdx.x * 64;
    const int row = tid >> 2, colw = tid & 3;   // staging role
    const int swz = (row & 7) << 4;
    f32x4 acc[4] = {};

    for (int k0 = 0; k0 < K; k0 += 64) {
        {   // stage A (row-guarded)
            uint4 v0 = {}, v1 = {};
            if (m0 + row < M) {
                const unsigned short* src = A + (size_t)(m0 + row) * K + k0 + colw * 16;
                v0 = *(const uint4*)src;
                v1 = *(const uint4*)(src + 8);
            }
            *(uint4*)(As + row * 128 + ((colw * 32) ^ swz)) = v0;
            *(uint4*)(As + row * 128 + ((colw * 32 + 16) ^ swz)) = v1;
        }
        {   // stage Bt
            uint4 v0 = {}, v1 = {};
            if (n0 + row < N) {
                const unsigned short* src = Bt + (size_t)(n0 + row) * K + k0 + colw * 16;
                v0 = *(const uint4*)src;
                v1 = *(const uint4*)(src + 8);
            }
            *(uint4*)(Bs + row * 128 + ((colw * 32) ^ swz)) = v0;
            *(uint4*)(Bs + row * 128 + ((colw * 32 + 16) ^ swz)) = v1;
        }
        __syncthreads();
        #pragma unroll
        for (int ks = 0; ks < 2; ++ks) {
            const int arow = wave * 16 + r;
            bf16x8 va = *(const bf16x8*)(As + arow * 128 + (((ks * 64) + kg * 16) ^ ((arow & 7) << 4)));
            #pragma unroll
            for (int nt = 0; nt < 4; ++nt) {
                const int brow = nt * 16 + r;
                bf16x8 vb = *(const bf16x8*)(Bs + brow * 128 + (((ks * 64) + kg * 16) ^ ((brow & 7) << 4)));
                acc[nt] = __builtin_amdgcn_mfma_f32_16x16x32_bf16(va, vb, acc[nt], 0, 0, 0);
            }
        }
        __syncthreads();
    }

    #pragma unroll
    for (int nt = 0; nt < 4; ++nt) {
        #pragma unroll
        for (int q = 0; q < 4; ++q) {
            int gr = m0 + wave * 16 + kg * 4 + q;
            int gc = n0 + nt * 16 + r;
            if (gr < M && gc < N) {
                float v = acc[nt][q];
                if (bias) v += bias[gc];
                if (RELU) v = fmaxf(v, 0.0f);
                if (Cf) Cf[(size_t)gr * N + gc] = v;
                if (Cb) Cb[(size_t)gr * N + gc] = f2bf_u16(v);
            }
        }
    }
}

// K6: masked row-max/argmax over affinity + label propagation
__global__ __launch_bounds__(256) void k_prop(const float* __restrict__ aff,
                                              const int* __restrict__ lab,
                                              const float* __restrict__ invn,
                                              float* __restrict__ out) {
    int i = blockIdx.x;
    float invi = invn[i];
    float best = -INFINITY;
    int bidx = 0;
    for (int j = threadIdx.x; j < NSEG; j += 256) {
        if (lab[j] != 0) {
            float v = aff[(size_t)i * NSEG + j] * invi * invn[j];
            if (v > best) { best = v; bidx = j; }
        }
    }
    __shared__ float bv[256];
    __shared__ int bi[256];
    bv[threadIdx.x] = best;
    bi[threadIdx.x] = bidx;
    __syncthreads();
    for (int st = 128; st > 0; st >>= 1) {
        if (threadIdx.x < st) {
            float v2 = bv[threadIdx.x + st];
            int i2 = bi[threadIdx.x + st];
            if (v2 > bv[threadIdx.x] ||
                (v2 == bv[threadIdx.x] && i2 < bi[threadIdx.x])) {
                bv[threadIdx.x] = v2;
                bi[threadIdx.x] = i2;
            }
        }
        __syncthreads();
    }
    if (threadIdx.x == 0) {
        int li = lab[i];
        int nl = li;
        if (li == 0 && bv[0] >= SIM_THRESH) nl = lab[bi[0]];
        out[2132 + i] = (float)nl;
    }
}

// K7: final 32->2 head + softmax -> preds
__global__ __launch_bounds__(256) void k_head(const float* __restrict__ h3,
                                              const float* __restrict__ wc,
                                              const float* __restrict__ bc,
                                              float* __restrict__ out) {
    int s = blockIdx.x * 256 + threadIdx.x;
    if (s >= NSEG) return;
    float z0 = bc[0], z1 = bc[1];
    #pragma unroll
    for (int k = 0; k < 32; k++) {
        float h = h3[s * 32 + k];
        z0 += h * wc[k * 2 + 0];
        z1 += h * wc[k * 2 + 1];
    }
    float m = fmaxf(z0, z1);
    float e0 = expf(z0 - m), e1 = expf(z1 - m);
    float inv = 1.0f / (e0 + e1);
    out[s * 2 + 0] = e0 * inv;
    out[s * 2 + 1] = e1 * inv;
}

extern "C" void kernel_launch(void* const* d_in, const int* in_sizes, int n_in,
                              void* d_out, int out_size, void* d_ws, size_t ws_size,
                              hipStream_t stream) {
    const float* fm = (const float*)d_in[0];
    const int* sp   = (const int*)d_in[1];
    const int* y    = (const int*)d_in[2];
    const float* w1 = (const float*)d_in[3];
    const float* b1 = (const float*)d_in[4];
    const float* w2 = (const float*)d_in[5];
    const float* b2 = (const float*)d_in[6];
    const float* w3 = (const float*)d_in[7];
    const float* b3 = (const float*)d_in[8];
    const float* wc = (const float*)d_in[9];
    const float* bc = (const float*)d_in[10];
    float* out = (float*)d_out;
    char* ws = (char*)d_ws;

    size_t off = 0;
    auto alloc = [&](size_t bytes) {
        size_t o = off;
        off += (bytes + 255) & ~(size_t)255;
        return o;
    };
    float*          feat   = (float*)(ws + alloc((size_t)544 * CFEAT * 4));
    unsigned short* featbf = (unsigned short*)(ws + alloc((size_t)544 * CFEAT * 2));
    unsigned short* w1T    = (unsigned short*)(ws + alloc((size_t)1024 * CFEAT * 2));
    unsigned short* w2T    = (unsigned short*)(ws + alloc((size_t)1024 * 1024 * 2));
    unsigned short* w3T    = (unsigned short*)(ws + alloc((size_t)32 * 1024 * 2));
    unsigned short* h1bf   = (unsigned short*)(ws + alloc((size_t)544 * 1024 * 2));
    unsigned short* h2bf   = (unsigned short*)(ws + alloc((size_t)544 * 1024 * 2));
    float*          h3     = (float*)(ws + alloc((size_t)544 * 32 * 4));
    float*          aff    = (float*)(ws + alloc((size_t)NSEG * NSEG * 4));
    int*            c3     = (int*)(ws + alloc((size_t)NSEG * 3 * 4));
    int*            lab    = (int*)(ws + alloc((size_t)NSEG * 4));
    float*          invc   = (float*)(ws + alloc((size_t)NSEG * 4));
    float*          invn   = (float*)(ws + alloc((size_t)NSEG * 4));

    hipMemsetAsync(feat, 0, (size_t)NSEG * CFEAT * 4, stream);
    hipMemsetAsync(c3, 0, (size_t)NSEG * 3 * 4, stream);

    // one-off weight transpose+convert (independent of segsum)
    k_cvtT<<<dim3(1024 / 32, CFEAT / 32), 256, 0, stream>>>(w1, w1T, CFEAT, 1024);
    k_cvtT<<<dim3(1024 / 32, 1024 / 32), 256, 0, stream>>>(w2, w2T, 1024, 1024);
    k_cvtT<<<dim3(32 / 32, 1024 / 32), 256, 0, stream>>>(w3, w3T, 1024, 32);

    k_counts<<<(PIX + 255) / 256, 256, 0, stream>>>(sp, y, c3);
    k_labels<<<3, 256, 0, stream>>>(c3, lab, invc, out);
    k_segsum_mfma<<<dim3(CFEAT / 64, KC), 256, 0, stream>>>(fm, sp, feat);
    k_mean<<<NSEG, 256, 0, stream>>>(feat, featbf, invc, invn);

    gemm_bf16<1><<<dim3(16, 9), 256, 0, stream>>>(featbf, w1T, b1, nullptr, h1bf, NSEG, 1024, CFEAT);
    gemm_bf16<1><<<dim3(16, 9), 256, 0, stream>>>(h1bf, w2T, b2, nullptr, h2bf, NSEG, 1024, 1024);
    gemm_bf16<1><<<dim3(1, 9), 256, 0, stream>>>(h2bf, w3T, b3, h3, nullptr, NSEG, 32, 1024);
    gemm_bf16<0><<<dim3(9, 9), 256, 0, stream>>>(featbf, featbf, nullptr, aff, nullptr, NSEG, NSEG, CFEAT);

    k_head<<<3, 256, 0, stream>>>(h3, wc, bc, out);
    k_prop<<<NSEG, 256, 0, stream>>>(aff, lab, invn, out);
}